// Round 7
// baseline (826.329 us; speedup 1.0000x reference)
//
#include <hip/hip_runtime.h>

typedef _Float16 half8 __attribute__((ext_vector_type(8)));
typedef __fp16 fp16x2 __attribute__((ext_vector_type(2)));
typedef float floatx4 __attribute__((ext_vector_type(4)));
typedef unsigned int uint;
typedef uint uint4t __attribute__((ext_vector_type(4)));

namespace {
constexpr int TT = 48, HID = 64, MH = 32, MS = 20;
constexpr int VSTR = 72;    // halves per vT row (144 B, conflict-free b128)
constexpr int PMSTR = 40;   // halves per phase-A P row
constexpr int WAVE_LDS = 4608;    // per-wave slice: vT [32][72]; phase-A pm aliases it
constexpr int NWAVES = 4;         // waves per block (independent bn, same expert)
constexpr int LDS_BYTES = WAVE_LDS * NWAVES;   // 18432 -> 8 blocks/CU = 32 waves/CU
// d_ws offsets in half elements (total 32768 halves = 64 KiB)
constexpr int WS_WV   = 0;        // value_w B-frags: [e][kk][nb] * 512
constexpr int WS_MEMA = 6144;     // mem A-frags (rows s, zero s>=20): 1024
constexpr int WS_MEMB = 7168;     // mem B-frags (k=s, col m, zero s>=20): 1024
constexpr int WS_M    = 8192;     // M^T A-frags: [e][hl][tbG][ak] * 512 = 24576
}

static __device__ inline uint pk2(float a, float b) {
    fp16x2 h = __builtin_amdgcn_cvt_pkrtz(a, b);
    return __builtin_bit_cast(uint, h);
}
static __device__ inline half8 mk8(uint a, uint b, uint c, uint d) {
    uint4t u = {a, b, c, d};
    return __builtin_bit_cast(half8, u);
}

// Prep: per-expert M = Wq*Wk^T (fp32) -> M^T A-frags hi/lo; value_w B-frags; mem frags.
__global__ __launch_bounds__(256)
void prep_frags(const float* __restrict__ hid_query,
                const float* __restrict__ key_w,
                const float* __restrict__ value_w,
                const float* __restrict__ memory,
                _Float16* __restrict__ ws)
{
    const int e = blockIdx.x, tid = threadIdx.x;
    __shared__ float sWq[HID * MH], sWk[HID * MH], sM[HID * HID];
    for (int i = tid; i < HID * MH; i += 256) {
        sWq[i] = hid_query[e * HID * MH + i];
        sWk[i] = key_w[e * HID * MH + i];
    }
    __syncthreads();
    for (int i = tid; i < HID * HID; i += 256) {
        int a = i >> 6, b = i & 63;
        float acc = 0.f;
        #pragma unroll
        for (int m = 0; m < MH; ++m) acc = fmaf(sWq[a * MH + m], sWk[b * MH + m], acc);
        sM[i] = acc;
    }
    __syncthreads();
    // M^T A-frags: lane l elem j of frag [hl][tbG][ak] = M[32ak+8*(l>>4)+j][16tbG+(l&15)]
    for (int i = tid; i < 16 * 512; i += 256) {
        int j = i & 7, lane = (i >> 3) & 63, ak = (i >> 9) & 1, tbG = (i >> 10) & 3, hl = (i >> 12) & 1;
        float v = sM[(32 * ak + 8 * (lane >> 4) + j) * 64 + 16 * tbG + (lane & 15)];
        _Float16 hi = (_Float16)v;
        ws[WS_M + (size_t)((((e * 2 + hl) * 4 + tbG) * 2 + ak) << 9) + (i & 511)] =
            hl ? (_Float16)(v - (float)hi) : hi;
    }
    // value_w B-frags: frag [kk][nb]: W[kk*32+(l>>4)*8+j][nb*16+(l&15)]
    for (int i = tid; i < 2048; i += 256) {
        int j = i & 7, lane = (i >> 3) & 63, nb = (i >> 9) & 1, kk = (i >> 10) & 1;
        int h = kk * 32 + (lane >> 4) * 8 + j;
        int m = nb * 16 + (lane & 15);
        ws[WS_WV + e * 2048 + (i & 2047)] = (_Float16)value_w[((size_t)e * HID + h) * MH + m];
    }
    if (e == 0) {
        for (int i = tid; i < 1024; i += 256) {
            int j = i & 7, lane = (i >> 3) & 63, sb = i >> 9;
            int s = 16 * sb + (lane & 15);
            int m = (lane >> 4) * 8 + j;
            ws[WS_MEMA + i] = (s < MS) ? (_Float16)memory[s * MH + m] : (_Float16)0.f;
        }
        for (int i = tid; i < 1024; i += 256) {
            int j = i & 7, lane = (i >> 3) & 63, nb = i >> 9;
            int s = (lane >> 4) * 8 + j;
            int m = 16 * nb + (lane & 15);
            ws[WS_MEMB + i] = (s < MS) ? (_Float16)memory[s * MH + m] : (_Float16)0.f;
        }
    }
}

// 4 independent waves per block (bn = blockIdx.x*4+wid, e = blockIdx.y).
// No barriers; each wave owns a private 4608 B LDS slice. 32 waves/CU.
__global__ __launch_bounds__(256, 8)
void testam_wave(const float* __restrict__ input,
                 const float* __restrict__ h0,
                 const float* __restrict__ h1,
                 const float* __restrict__ h2,
                 const float* __restrict__ input_query,
                 const _Float16* __restrict__ ws,
                 float* __restrict__ out)
{
    __shared__ __align__(16) char smem[LDS_BYTES];
    const int tid  = threadIdx.x;
    const int wid  = tid >> 6;
    const int lane = tid & 63;
    const int r = lane & 15, g = lane >> 4;
    const size_t bn = (size_t)blockIdx.x * NWAVES + wid;
    const int e = blockIdx.y;

    char* wb = smem + wid * WAVE_LDS;
    _Float16* s_vt = (_Float16*)wb;   // [32][72] halves
    _Float16* s_pm = (_Float16*)wb;   // phase-A P [48][40] (aliases vT; vT dead by then)

    const float* hp = (e == 0) ? h0 : (e == 1 ? h1 : h2);
    const float* hb = hp + bn * (size_t)(TT * HID);

    // ---- h A-frags, hi/lo f16 split ----
    half8 Ahi[3][2], Alo[3][2];
    #pragma unroll
    for (int tb = 0; tb < 3; ++tb)
        #pragma unroll
        for (int kk = 0; kk < 2; ++kk) {
            const float* src = hb + (tb * 16 + r) * HID + kk * 32 + g * 8;
            float4 x0 = *(const float4*)src;
            float4 x1 = *(const float4*)(src + 4);
            float xs[8] = {x0.x, x0.y, x0.z, x0.w, x1.x, x1.y, x1.z, x1.w};
            half8 hi, lo;
            #pragma unroll
            for (int j = 0; j < 8; ++j) {
                _Float16 hh = (_Float16)xs[j];
                hi[j] = hh;
                lo[j] = (_Float16)(xs[j] - (float)hh);
            }
            Ahi[tb][kk] = hi; Alo[tb][kk] = lo;
        }

    // ---- v projection -> vT LDS (B-operand of PV) ----
    {
        half8 WV[2][2];
        #pragma unroll
        for (int kk = 0; kk < 2; ++kk)
            #pragma unroll
            for (int nb = 0; nb < 2; ++nb)
                WV[kk][nb] = *(const half8*)(ws + WS_WV + e * 2048 + (size_t)((kk * 2 + nb) * 64 + lane) * 8);
        floatx4 vacc[3][2];
        #pragma unroll
        for (int tb = 0; tb < 3; ++tb) { vacc[tb][0] = (floatx4)0.f; vacc[tb][1] = (floatx4)0.f; }
        #pragma unroll
        for (int kk = 0; kk < 2; ++kk)
            #pragma unroll
            for (int tb = 0; tb < 3; ++tb)
                #pragma unroll
                for (int nb = 0; nb < 2; ++nb) {
                    vacc[tb][nb] = __builtin_amdgcn_mfma_f32_16x16x32_f16(Alo[tb][kk], WV[kk][nb], vacc[tb][nb], 0, 0, 0);
                    vacc[tb][nb] = __builtin_amdgcn_mfma_f32_16x16x32_f16(Ahi[tb][kk], WV[kk][nb], vacc[tb][nb], 0, 0, 0);
                }
        #pragma unroll
        for (int tb = 0; tb < 3; ++tb)
            #pragma unroll
            for (int nb = 0; nb < 2; ++nb)
                #pragma unroll
                for (int rr = 0; rr < 4; ++rr)
                    s_vt[(nb * 16 + r) * VSTR + tb * 16 + g * 4 + rr] = (_Float16)vacc[tb][nb][rr];
        #pragma unroll
        for (int i = lane; i < 32 * 8; i += 64) {   // zero pad rows s=48..63
            int row = i >> 3, c = 48 + ((i & 7) << 1);
            *(uint*)&s_vt[row * VSTR + c] = 0u;
        }
    }
    asm volatile("" ::: "memory");

    // ---- E' = energy^T via G^T = M^T h^T (all in registers) ----
    const int laneA = (g & 1) * 32 + r;   // src lane for j<4 in the cheap regroup
    const bool hiT = (g >= 2);

    floatx4 E[3][3];
    #pragma unroll
    for (int tb = 0; tb < 3; ++tb)
        #pragma unroll
        for (int nb = 0; nb < 3; ++nb) E[tb][nb] = (floatx4)0.f;

    #pragma unroll
    for (int kk = 0; kk < 2; ++kk) {
        floatx4 Gacc[2][3];
        #pragma unroll
        for (int t = 0; t < 2; ++t)
            #pragma unroll
            for (int nb = 0; nb < 3; ++nb) Gacc[t][nb] = (floatx4)0.f;
        #pragma unroll
        for (int tbL = 0; tbL < 2; ++tbL) {
            const int tbG = kk * 2 + tbL;
            #pragma unroll
            for (int ak = 0; ak < 2; ++ak) {
                half8 Mhi = *(const half8*)(ws + WS_M + (size_t)(((((e * 2 + 0) * 4 + tbG) * 2 + ak) * 64 + lane)) * 8);
                half8 Mlo = *(const half8*)(ws + WS_M + (size_t)(((((e * 2 + 1) * 4 + tbG) * 2 + ak) * 64 + lane)) * 8);
                #pragma unroll
                for (int nb = 0; nb < 3; ++nb) {
                    Gacc[tbL][nb] = __builtin_amdgcn_mfma_f32_16x16x32_f16(Mlo, Ahi[nb][ak], Gacc[tbL][nb], 0, 0, 0);
                    Gacc[tbL][nb] = __builtin_amdgcn_mfma_f32_16x16x32_f16(Mhi, Alo[nb][ak], Gacc[tbL][nb], 0, 0, 0);
                    Gacc[tbL][nb] = __builtin_amdgcn_mfma_f32_16x16x32_f16(Mhi, Ahi[nb][ak], Gacc[tbL][nb], 0, 0, 0);
                }
            }
        }
        // regroup G^T C-layout -> B-frags (hi/lo): 2 shfl + 1 select per dword
        #pragma unroll
        for (int nb = 0; nb < 3; ++nb) {
            uint pkh[2][2], pkl[2][2];
            #pragma unroll
            for (int t = 0; t < 2; ++t)
                #pragma unroll
                for (int d = 0; d < 2; ++d) {
                    float x0 = Gacc[t][nb][2 * d], x1 = Gacc[t][nb][2 * d + 1];
                    fp16x2 h = __builtin_amdgcn_cvt_pkrtz(x0, x1);
                    pkh[t][d] = __builtin_bit_cast(uint, h);
                    pkl[t][d] = pk2(x0 - (float)h[0], x1 - (float)h[1]);
                }
            uint wh[4], wl[4];
            #pragma unroll
            for (int d = 0; d < 2; ++d) {
                int h0a = __shfl((int)pkh[0][d], laneA);
                int h1a = __shfl((int)pkh[1][d], laneA);
                int h0b = __shfl((int)pkh[0][d], laneA + 16);
                int h1b = __shfl((int)pkh[1][d], laneA + 16);
                wh[d]     = hiT ? (uint)h1a : (uint)h0a;
                wh[2 + d] = hiT ? (uint)h1b : (uint)h0b;
                int l0a = __shfl((int)pkl[0][d], laneA);
                int l1a = __shfl((int)pkl[1][d], laneA);
                int l0b = __shfl((int)pkl[0][d], laneA + 16);
                int l1b = __shfl((int)pkl[1][d], laneA + 16);
                wl[d]     = hiT ? (uint)l1a : (uint)l0a;
                wl[2 + d] = hiT ? (uint)l1b : (uint)l0b;
            }
            half8 Bhi = mk8(wh[0], wh[1], wh[2], wh[3]);
            half8 Blo = mk8(wl[0], wl[1], wl[2], wl[3]);
            #pragma unroll
            for (int tb = 0; tb < 3; ++tb) {
                E[tb][nb] = __builtin_amdgcn_mfma_f32_16x16x32_f16(Alo[tb][kk], Bhi, E[tb][nb], 0, 0, 0);
                E[tb][nb] = __builtin_amdgcn_mfma_f32_16x16x32_f16(Ahi[tb][kk], Blo, E[tb][nb], 0, 0, 0);
                E[tb][nb] = __builtin_amdgcn_mfma_f32_16x16x32_f16(Ahi[tb][kk], Bhi, E[tb][nb], 0, 0, 0);
            }
        }
    }

    // ---- softmax over s (rows of E') per t-col; numerators only ----
    #pragma unroll
    for (int nb = 0; nb < 3; ++nb) {
        float m = E[0][nb][0];
        #pragma unroll
        for (int tb = 0; tb < 3; ++tb)
            #pragma unroll
            for (int rr = 0; rr < 4; ++rr) m = fmaxf(m, E[tb][nb][rr]);
        m = fmaxf(m, __shfl_xor(m, 16));
        m = fmaxf(m, __shfl_xor(m, 32));
        #pragma unroll
        for (int tb = 0; tb < 3; ++tb)
            #pragma unroll
            for (int rr = 0; rr < 4; ++rr) E[tb][nb][rr] = __expf(E[tb][nb][rr] - m);
    }

    // ---- P'^T A-frags via the same cheap regroup (no LDS) ----
    half8 PF[3][2];
    #pragma unroll
    for (int tbT = 0; tbT < 3; ++tbT) {
        uint pk[3][2];
        #pragma unroll
        for (int t = 0; t < 3; ++t)
            #pragma unroll
            for (int d = 0; d < 2; ++d)
                pk[t][d] = pk2(E[t][tbT][2 * d], E[t][tbT][2 * d + 1]);
        uint w0[4], w1[4];
        #pragma unroll
        for (int d = 0; d < 2; ++d) {
            int a0 = __shfl((int)pk[0][d], laneA);
            int a1 = __shfl((int)pk[1][d], laneA);
            int b0 = __shfl((int)pk[0][d], laneA + 16);
            int b1 = __shfl((int)pk[1][d], laneA + 16);
            w0[d]     = hiT ? (uint)a1 : (uint)a0;
            w0[2 + d] = hiT ? (uint)b1 : (uint)b0;
            int a2 = __shfl((int)pk[2][d], laneA);
            int b2 = __shfl((int)pk[2][d], laneA + 16);
            w1[d]     = hiT ? 0u : (uint)a2;     // rows s>=48 are zero pad
            w1[2 + d] = hiT ? 0u : (uint)b2;
        }
        PF[tbT][0] = mk8(w0[0], w0[1], w0[2], w0[3]);
        PF[tbT][1] = mk8(w1[0], w1[1], w1[2], w1[3]);
    }

    // ---- att = P'^T @ v ----
    floatx4 att[3][2];
    #pragma unroll
    for (int tb = 0; tb < 3; ++tb) { att[tb][0] = (floatx4)0.f; att[tb][1] = (floatx4)0.f; }
    #pragma unroll
    for (int kk = 0; kk < 2; ++kk) {
        half8 vb0 = *(const half8*)&s_vt[(0 * 16 + r) * VSTR + kk * 32 + g * 8];
        half8 vb1 = *(const half8*)&s_vt[(1 * 16 + r) * VSTR + kk * 32 + g * 8];
        #pragma unroll
        for (int tb = 0; tb < 3; ++tb) {
            att[tb][0] = __builtin_amdgcn_mfma_f32_16x16x32_f16(PF[tb][kk], vb0, att[tb][0], 0, 0, 0);
            att[tb][1] = __builtin_amdgcn_mfma_f32_16x16x32_f16(PF[tb][kk], vb1, att[tb][1], 0, 0, 0);
        }
    }
    asm volatile("" ::: "memory");   // vT dead; s_pm may now overwrite it

    // ---- phase A (at end): memory read-out, all-MFMA ----
    half8 memA0 = *(const half8*)(ws + WS_MEMA + (size_t)lane * 8);
    half8 memA1 = *(const half8*)(ws + WS_MEMA + (size_t)(64 + lane) * 8);
    half8 memB0 = *(const half8*)(ws + WS_MEMB + (size_t)lane * 8);
    half8 memB1 = *(const half8*)(ws + WS_MEMB + (size_t)(64 + lane) * 8);

    float4 iqa = *(const float4*)(input_query + g * 8);
    float4 iqb = *(const float4*)(input_query + g * 8 + 4);
    float4 iqc = *(const float4*)(input_query + 32 + g * 8);
    float4 iqd = *(const float4*)(input_query + 32 + g * 8 + 4);
    float iq0[8] = {iqa.x, iqa.y, iqa.z, iqa.w, iqb.x, iqb.y, iqb.z, iqb.w};
    float iq1[8] = {iqc.x, iqc.y, iqc.z, iqc.w, iqd.x, iqd.y, iqd.z, iqd.w};

    floatx4 Em[2][3];
    #pragma unroll
    for (int tb = 0; tb < 3; ++tb) {
        const float2 in2 = *(const float2*)(input + bn * 96 + (16 * tb + r) * 2);
        half8 qb;
        #pragma unroll
        for (int j = 0; j < 8; ++j)
            qb[j] = (_Float16)(in2.x * iq0[j] + in2.y * iq1[j]);
        Em[0][tb] = __builtin_amdgcn_mfma_f32_16x16x32_f16(memA0, qb, (floatx4)0.f, 0, 0, 0);
        Em[1][tb] = __builtin_amdgcn_mfma_f32_16x16x32_f16(memA1, qb, (floatx4)0.f, 0, 0, 0);
    }
    #pragma unroll
    for (int tb = 0; tb < 3; ++tb) {
        float mx = Em[0][tb][0];
        #pragma unroll
        for (int rr = 1; rr < 4; ++rr) mx = fmaxf(mx, Em[0][tb][rr]);
        #pragma unroll
        for (int rr = 0; rr < 4; ++rr) mx = fmaxf(mx, Em[1][tb][rr]);
        mx = fmaxf(mx, __shfl_xor(mx, 16));
        mx = fmaxf(mx, __shfl_xor(mx, 32));
        #pragma unroll
        for (int sb = 0; sb < 2; ++sb)
            #pragma unroll
            for (int rr = 0; rr < 4; ++rr)
                s_pm[(16 * tb + r) * PMSTR + 16 * sb + 4 * g + rr] =
                    (_Float16)__expf(Em[sb][tb][rr] - mx);
    }
    asm volatile("" ::: "memory");
    floatx4 mems[3][2];
    #pragma unroll
    for (int tb = 0; tb < 3; ++tb) {
        half8 pA = *(const half8*)&s_pm[(16 * tb + r) * PMSTR + g * 8];
        mems[tb][0] = __builtin_amdgcn_mfma_f32_16x16x32_f16(pA, memB0, (floatx4)0.f, 0, 0, 0);
        mems[tb][1] = __builtin_amdgcn_mfma_f32_16x16x32_f16(pA, memB1, (floatx4)0.f, 0, 0, 0);
    }

    // ---- cosine(att, memories); reduce over m via 16-lane xor ----
    #pragma unroll
    for (int tb = 0; tb < 3; ++tb)
        #pragma unroll
        for (int rr = 0; rr < 4; ++rr) {
            int t = 16 * tb + 4 * g + rr;
            float a0 = att[tb][0][rr], a1 = att[tb][1][rr];
            float m0 = mems[tb][0][rr], m1 = mems[tb][1][rr];
            float nu = a0 * m0 + a1 * m1;
            float nr = a0 * a0 + a1 * a1;
            float nm = m0 * m0 + m1 * m1;
            nu += __shfl_xor(nu, 1); nr += __shfl_xor(nr, 1); nm += __shfl_xor(nm, 1);
            nu += __shfl_xor(nu, 2); nr += __shfl_xor(nr, 2); nm += __shfl_xor(nm, 2);
            nu += __shfl_xor(nu, 4); nr += __shfl_xor(nr, 4); nm += __shfl_xor(nm, 4);
            nu += __shfl_xor(nu, 8); nr += __shfl_xor(nr, 8); nm += __shfl_xor(nm, 8);
            if (r == 0) {
                float den = fmaxf(sqrtf(nr * nm), 1e-8f);
                out[(bn * TT + t) * 3 + e] = nu / den;
            }
        }
}

extern "C" void kernel_launch(void* const* d_in, const int* in_sizes, int n_in,
                              void* d_out, int out_size, void* d_ws, size_t ws_size,
                              hipStream_t stream) {
    const float* input       = (const float*)d_in[0];
    const float* h0          = (const float*)d_in[1];
    const float* h1          = (const float*)d_in[2];
    const float* h2          = (const float*)d_in[3];
    const float* memory      = (const float*)d_in[4];
    const float* input_query = (const float*)d_in[5];
    const float* hid_query   = (const float*)d_in[6];
    const float* key_w       = (const float*)d_in[7];
    const float* value_w     = (const float*)d_in[8];
    float* out = (float*)d_out;
    _Float16* ws = (_Float16*)d_ws;   // 65536 bytes used

    hipLaunchKernelGGL(prep_frags, dim3(3), dim3(256), 0, stream,
                       hid_query, key_w, value_w, memory, ws);
    hipLaunchKernelGGL(testam_wave, dim3(16 * 1024 / NWAVES, 3), dim3(256), 0, stream,
                       input, h0, h1, h2, input_query, ws, out);
}

// Round 8
// 222.990 us; speedup vs baseline: 3.7057x; 3.7057x over previous
//
#include <hip/hip_runtime.h>

typedef _Float16 half8 __attribute__((ext_vector_type(8)));
typedef __fp16 fp16x2 __attribute__((ext_vector_type(2)));
typedef float floatx4 __attribute__((ext_vector_type(4)));
typedef unsigned int uint;
typedef uint uint4t __attribute__((ext_vector_type(4)));

namespace {
constexpr int TT = 48, HID = 64, MH = 32, MS = 20;
constexpr int VSTR = 72;    // halves per vT row (144 B, conflict-free b128)
constexpr int PMSTR = 40;   // halves per phase-A P row
constexpr int WAVE_LDS = 4608;    // per-wave slice: vT [32][72]; phase-A pm aliases it
constexpr int NWAVES = 2;         // waves per block (independent bn, same expert)
constexpr int LDS_BYTES = WAVE_LDS * NWAVES;   // 9216 B
// d_ws offsets in half elements (total 32768 halves = 64 KiB)
constexpr int WS_WV   = 0;        // value_w B-frags: [e][kk][nb] * 512
constexpr int WS_MEMA = 6144;     // mem A-frags (rows s, zero s>=20): 1024
constexpr int WS_MEMB = 7168;     // mem B-frags (k=s, col m, zero s>=20): 1024
constexpr int WS_M    = 8192;     // M^T A-frags: [e][hl][tbG][ak] * 512 = 24576
}

static __device__ inline uint pk2(float a, float b) {
    fp16x2 h = __builtin_amdgcn_cvt_pkrtz(a, b);
    return __builtin_bit_cast(uint, h);
}
static __device__ inline half8 mk8(uint a, uint b, uint c, uint d) {
    uint4t u = {a, b, c, d};
    return __builtin_bit_cast(half8, u);
}

// Prep: per-expert M = Wq*Wk^T (fp32) -> M^T A-frags hi/lo; value_w B-frags; mem frags.
__global__ __launch_bounds__(256)
void prep_frags(const float* __restrict__ hid_query,
                const float* __restrict__ key_w,
                const float* __restrict__ value_w,
                const float* __restrict__ memory,
                _Float16* __restrict__ ws)
{
    const int e = blockIdx.x, tid = threadIdx.x;
    __shared__ float sWq[HID * MH], sWk[HID * MH], sM[HID * HID];
    for (int i = tid; i < HID * MH; i += 256) {
        sWq[i] = hid_query[e * HID * MH + i];
        sWk[i] = key_w[e * HID * MH + i];
    }
    __syncthreads();
    for (int i = tid; i < HID * HID; i += 256) {
        int a = i >> 6, b = i & 63;
        float acc = 0.f;
        #pragma unroll
        for (int m = 0; m < MH; ++m) acc = fmaf(sWq[a * MH + m], sWk[b * MH + m], acc);
        sM[i] = acc;
    }
    __syncthreads();
    // M^T A-frags: lane l elem j of frag [hl][tbG][ak] = M[32ak+8*(l>>4)+j][16tbG+(l&15)]
    for (int i = tid; i < 16 * 512; i += 256) {
        int j = i & 7, lane = (i >> 3) & 63, ak = (i >> 9) & 1, tbG = (i >> 10) & 3, hl = (i >> 12) & 1;
        float v = sM[(32 * ak + 8 * (lane >> 4) + j) * 64 + 16 * tbG + (lane & 15)];
        _Float16 hi = (_Float16)v;
        ws[WS_M + (size_t)((((e * 2 + hl) * 4 + tbG) * 2 + ak) << 9) + (i & 511)] =
            hl ? (_Float16)(v - (float)hi) : hi;
    }
    // value_w B-frags: frag [kk][nb]: W[kk*32+(l>>4)*8+j][nb*16+(l&15)]
    for (int i = tid; i < 2048; i += 256) {
        int j = i & 7, lane = (i >> 3) & 63, nb = (i >> 9) & 1, kk = (i >> 10) & 1;
        int h = kk * 32 + (lane >> 4) * 8 + j;
        int m = nb * 16 + (lane & 15);
        ws[WS_WV + e * 2048 + (i & 2047)] = (_Float16)value_w[((size_t)e * HID + h) * MH + m];
    }
    if (e == 0) {
        for (int i = tid; i < 1024; i += 256) {
            int j = i & 7, lane = (i >> 3) & 63, sb = i >> 9;
            int s = 16 * sb + (lane & 15);
            int m = (lane >> 4) * 8 + j;
            ws[WS_MEMA + i] = (s < MS) ? (_Float16)memory[s * MH + m] : (_Float16)0.f;
        }
        for (int i = tid; i < 1024; i += 256) {
            int j = i & 7, lane = (i >> 3) & 63, nb = i >> 9;
            int s = (lane >> 4) * 8 + j;
            int m = 16 * nb + (lane & 15);
            ws[WS_MEMB + i] = (s < MS) ? (_Float16)memory[s * MH + m] : (_Float16)0.f;
        }
    }
}

// 2 independent waves per block (bn = blockIdx.x*2+wid, e = blockIdx.y).
// No barriers; each wave owns a private 4608 B LDS slice.
__global__ __launch_bounds__(128, 4)
void testam_wave(const float* __restrict__ input,
                 const float* __restrict__ h0,
                 const float* __restrict__ h1,
                 const float* __restrict__ h2,
                 const float* __restrict__ input_query,
                 const _Float16* __restrict__ ws,
                 float* __restrict__ out)
{
    __shared__ __align__(16) char smem[LDS_BYTES];
    const int tid  = threadIdx.x;
    const int wid  = tid >> 6;
    const int lane = tid & 63;
    const int r = lane & 15, g = lane >> 4;
    const size_t bn = (size_t)blockIdx.x * NWAVES + wid;
    const int e = blockIdx.y;

    char* wb = smem + wid * WAVE_LDS;
    _Float16* s_vt = (_Float16*)wb;   // [32][72] halves
    _Float16* s_pm = (_Float16*)wb;   // phase-A P [48][40] (aliases vT; vT dead by then)

    const float* hp = (e == 0) ? h0 : (e == 1 ? h1 : h2);
    const float* hb = hp + bn * (size_t)(TT * HID);

    // ---- h A-frags, single f16 (precision budget: ~3e-3 E-error, OK vs 1.5e-2) ----
    half8 Ah[3][2];
    #pragma unroll
    for (int tb = 0; tb < 3; ++tb)
        #pragma unroll
        for (int kk = 0; kk < 2; ++kk) {
            const float* src = hb + (tb * 16 + r) * HID + kk * 32 + g * 8;
            float4 x0 = *(const float4*)src;
            float4 x1 = *(const float4*)(src + 4);
            half8 hi;
            hi[0] = (_Float16)x0.x; hi[1] = (_Float16)x0.y;
            hi[2] = (_Float16)x0.z; hi[3] = (_Float16)x0.w;
            hi[4] = (_Float16)x1.x; hi[5] = (_Float16)x1.y;
            hi[6] = (_Float16)x1.z; hi[7] = (_Float16)x1.w;
            Ah[tb][kk] = hi;
        }

    // ---- v projection -> vT LDS (B-operand of PV) ----
    {
        half8 WV[2][2];
        #pragma unroll
        for (int kk = 0; kk < 2; ++kk)
            #pragma unroll
            for (int nb = 0; nb < 2; ++nb)
                WV[kk][nb] = *(const half8*)(ws + WS_WV + e * 2048 + (size_t)((kk * 2 + nb) * 64 + lane) * 8);
        floatx4 vacc[3][2];
        #pragma unroll
        for (int tb = 0; tb < 3; ++tb) { vacc[tb][0] = (floatx4)0.f; vacc[tb][1] = (floatx4)0.f; }
        #pragma unroll
        for (int kk = 0; kk < 2; ++kk)
            #pragma unroll
            for (int tb = 0; tb < 3; ++tb)
                #pragma unroll
                for (int nb = 0; nb < 2; ++nb)
                    vacc[tb][nb] = __builtin_amdgcn_mfma_f32_16x16x32_f16(Ah[tb][kk], WV[kk][nb], vacc[tb][nb], 0, 0, 0);
        #pragma unroll
        for (int tb = 0; tb < 3; ++tb)
            #pragma unroll
            for (int nb = 0; nb < 2; ++nb)
                #pragma unroll
                for (int rr = 0; rr < 4; ++rr)
                    s_vt[(nb * 16 + r) * VSTR + tb * 16 + g * 4 + rr] = (_Float16)vacc[tb][nb][rr];
        #pragma unroll
        for (int i = lane; i < 32 * 8; i += 64) {   // zero pad rows s=48..63
            int row = i >> 3, c = 48 + ((i & 7) << 1);
            *(uint*)&s_vt[row * VSTR + c] = 0u;
        }
    }
    asm volatile("" ::: "memory");

    // ---- E' = energy^T via G^T = M^T h^T (all in registers; M kept hi/lo) ----
    const int laneA = (g & 1) * 32 + r;   // src lane for j<4 in the cheap regroup
    const bool hiT = (g >= 2);

    floatx4 E[3][3];
    #pragma unroll
    for (int tb = 0; tb < 3; ++tb)
        #pragma unroll
        for (int nb = 0; nb < 3; ++nb) E[tb][nb] = (floatx4)0.f;

    #pragma unroll
    for (int kk = 0; kk < 2; ++kk) {
        floatx4 Gacc[2][3];
        #pragma unroll
        for (int t = 0; t < 2; ++t)
            #pragma unroll
            for (int nb = 0; nb < 3; ++nb) Gacc[t][nb] = (floatx4)0.f;
        #pragma unroll
        for (int tbL = 0; tbL < 2; ++tbL) {
            const int tbG = kk * 2 + tbL;
            #pragma unroll
            for (int ak = 0; ak < 2; ++ak) {
                half8 Mhi = *(const half8*)(ws + WS_M + (size_t)(((((e * 2 + 0) * 4 + tbG) * 2 + ak) * 64 + lane)) * 8);
                half8 Mlo = *(const half8*)(ws + WS_M + (size_t)(((((e * 2 + 1) * 4 + tbG) * 2 + ak) * 64 + lane)) * 8);
                #pragma unroll
                for (int nb = 0; nb < 3; ++nb) {
                    Gacc[tbL][nb] = __builtin_amdgcn_mfma_f32_16x16x32_f16(Mlo, Ah[nb][ak], Gacc[tbL][nb], 0, 0, 0);
                    Gacc[tbL][nb] = __builtin_amdgcn_mfma_f32_16x16x32_f16(Mhi, Ah[nb][ak], Gacc[tbL][nb], 0, 0, 0);
                }
            }
        }
        // regroup G^T C-layout -> B-frag (hi only): 2 shfl + 1 select per dword
        #pragma unroll
        for (int nb = 0; nb < 3; ++nb) {
            uint pkh[2][2];
            #pragma unroll
            for (int t = 0; t < 2; ++t)
                #pragma unroll
                for (int d = 0; d < 2; ++d)
                    pkh[t][d] = pk2(Gacc[t][nb][2 * d], Gacc[t][nb][2 * d + 1]);
            uint wh[4];
            #pragma unroll
            for (int d = 0; d < 2; ++d) {
                int h0a = __shfl((int)pkh[0][d], laneA);
                int h1a = __shfl((int)pkh[1][d], laneA);
                int h0b = __shfl((int)pkh[0][d], laneA + 16);
                int h1b = __shfl((int)pkh[1][d], laneA + 16);
                wh[d]     = hiT ? (uint)h1a : (uint)h0a;
                wh[2 + d] = hiT ? (uint)h1b : (uint)h0b;
            }
            half8 Bh = mk8(wh[0], wh[1], wh[2], wh[3]);
            #pragma unroll
            for (int tb = 0; tb < 3; ++tb)
                E[tb][nb] = __builtin_amdgcn_mfma_f32_16x16x32_f16(Ah[tb][kk], Bh, E[tb][nb], 0, 0, 0);
        }
    }

    // ---- softmax over s (rows of E') per t-col; numerators only ----
    #pragma unroll
    for (int nb = 0; nb < 3; ++nb) {
        float m = E[0][nb][0];
        #pragma unroll
        for (int tb = 0; tb < 3; ++tb)
            #pragma unroll
            for (int rr = 0; rr < 4; ++rr) m = fmaxf(m, E[tb][nb][rr]);
        m = fmaxf(m, __shfl_xor(m, 16));
        m = fmaxf(m, __shfl_xor(m, 32));
        #pragma unroll
        for (int tb = 0; tb < 3; ++tb)
            #pragma unroll
            for (int rr = 0; rr < 4; ++rr) E[tb][nb][rr] = __expf(E[tb][nb][rr] - m);
    }

    // ---- P'^T A-frags via the same cheap regroup (no LDS) ----
    half8 PF[3][2];
    #pragma unroll
    for (int tbT = 0; tbT < 3; ++tbT) {
        uint pk[3][2];
        #pragma unroll
        for (int t = 0; t < 3; ++t)
            #pragma unroll
            for (int d = 0; d < 2; ++d)
                pk[t][d] = pk2(E[t][tbT][2 * d], E[t][tbT][2 * d + 1]);
        uint w0[4], w1[4];
        #pragma unroll
        for (int d = 0; d < 2; ++d) {
            int a0 = __shfl((int)pk[0][d], laneA);
            int a1 = __shfl((int)pk[1][d], laneA);
            int b0 = __shfl((int)pk[0][d], laneA + 16);
            int b1 = __shfl((int)pk[1][d], laneA + 16);
            w0[d]     = hiT ? (uint)a1 : (uint)a0;
            w0[2 + d] = hiT ? (uint)b1 : (uint)b0;
            int a2 = __shfl((int)pk[2][d], laneA);
            int b2 = __shfl((int)pk[2][d], laneA + 16);
            w1[d]     = hiT ? 0u : (uint)a2;     // rows s>=48 are zero pad
            w1[2 + d] = hiT ? 0u : (uint)b2;
        }
        PF[tbT][0] = mk8(w0[0], w0[1], w0[2], w0[3]);
        PF[tbT][1] = mk8(w1[0], w1[1], w1[2], w1[3]);
    }

    // ---- att = P'^T @ v ----
    floatx4 att[3][2];
    #pragma unroll
    for (int tb = 0; tb < 3; ++tb) { att[tb][0] = (floatx4)0.f; att[tb][1] = (floatx4)0.f; }
    #pragma unroll
    for (int kk = 0; kk < 2; ++kk) {
        half8 vb0 = *(const half8*)&s_vt[(0 * 16 + r) * VSTR + kk * 32 + g * 8];
        half8 vb1 = *(const half8*)&s_vt[(1 * 16 + r) * VSTR + kk * 32 + g * 8];
        #pragma unroll
        for (int tb = 0; tb < 3; ++tb) {
            att[tb][0] = __builtin_amdgcn_mfma_f32_16x16x32_f16(PF[tb][kk], vb0, att[tb][0], 0, 0, 0);
            att[tb][1] = __builtin_amdgcn_mfma_f32_16x16x32_f16(PF[tb][kk], vb1, att[tb][1], 0, 0, 0);
        }
    }
    asm volatile("" ::: "memory");   // vT dead; s_pm may now overwrite it

    // ---- phase A (at end): memory read-out, all-MFMA ----
    half8 memA0 = *(const half8*)(ws + WS_MEMA + (size_t)lane * 8);
    half8 memA1 = *(const half8*)(ws + WS_MEMA + (size_t)(64 + lane) * 8);
    half8 memB0 = *(const half8*)(ws + WS_MEMB + (size_t)lane * 8);
    half8 memB1 = *(const half8*)(ws + WS_MEMB + (size_t)(64 + lane) * 8);

    float4 iqa = *(const float4*)(input_query + g * 8);
    float4 iqb = *(const float4*)(input_query + g * 8 + 4);
    float4 iqc = *(const float4*)(input_query + 32 + g * 8);
    float4 iqd = *(const float4*)(input_query + 32 + g * 8 + 4);
    float iq0[8] = {iqa.x, iqa.y, iqa.z, iqa.w, iqb.x, iqb.y, iqb.z, iqb.w};
    float iq1[8] = {iqc.x, iqc.y, iqc.z, iqc.w, iqd.x, iqd.y, iqd.z, iqd.w};

    floatx4 Em[2][3];
    #pragma unroll
    for (int tb = 0; tb < 3; ++tb) {
        const float2 in2 = *(const float2*)(input + bn * 96 + (16 * tb + r) * 2);
        half8 qb;
        #pragma unroll
        for (int j = 0; j < 8; ++j)
            qb[j] = (_Float16)(in2.x * iq0[j] + in2.y * iq1[j]);
        Em[0][tb] = __builtin_amdgcn_mfma_f32_16x16x32_f16(memA0, qb, (floatx4)0.f, 0, 0, 0);
        Em[1][tb] = __builtin_amdgcn_mfma_f32_16x16x32_f16(memA1, qb, (floatx4)0.f, 0, 0, 0);
    }
    #pragma unroll
    for (int tb = 0; tb < 3; ++tb) {
        float mx = Em[0][tb][0];
        #pragma unroll
        for (int rr = 1; rr < 4; ++rr) mx = fmaxf(mx, Em[0][tb][rr]);
        #pragma unroll
        for (int rr = 0; rr < 4; ++rr) mx = fmaxf(mx, Em[1][tb][rr]);
        mx = fmaxf(mx, __shfl_xor(mx, 16));
        mx = fmaxf(mx, __shfl_xor(mx, 32));
        #pragma unroll
        for (int sb = 0; sb < 2; ++sb)
            #pragma unroll
            for (int rr = 0; rr < 4; ++rr)
                s_pm[(16 * tb + r) * PMSTR + 16 * sb + 4 * g + rr] =
                    (_Float16)__expf(Em[sb][tb][rr] - mx);
    }
    asm volatile("" ::: "memory");
    floatx4 mems[3][2];
    #pragma unroll
    for (int tb = 0; tb < 3; ++tb) {
        half8 pA = *(const half8*)&s_pm[(16 * tb + r) * PMSTR + g * 8];
        mems[tb][0] = __builtin_amdgcn_mfma_f32_16x16x32_f16(pA, memB0, (floatx4)0.f, 0, 0, 0);
        mems[tb][1] = __builtin_amdgcn_mfma_f32_16x16x32_f16(pA, memB1, (floatx4)0.f, 0, 0, 0);
    }

    // ---- cosine(att, memories); reduce over m via 16-lane xor ----
    #pragma unroll
    for (int tb = 0; tb < 3; ++tb)
        #pragma unroll
        for (int rr = 0; rr < 4; ++rr) {
            int t = 16 * tb + 4 * g + rr;
            float a0 = att[tb][0][rr], a1 = att[tb][1][rr];
            float m0 = mems[tb][0][rr], m1 = mems[tb][1][rr];
            float nu = a0 * m0 + a1 * m1;
            float nr = a0 * a0 + a1 * a1;
            float nm = m0 * m0 + m1 * m1;
            nu += __shfl_xor(nu, 1); nr += __shfl_xor(nr, 1); nm += __shfl_xor(nm, 1);
            nu += __shfl_xor(nu, 2); nr += __shfl_xor(nr, 2); nm += __shfl_xor(nm, 2);
            nu += __shfl_xor(nu, 4); nr += __shfl_xor(nr, 4); nm += __shfl_xor(nm, 4);
            nu += __shfl_xor(nu, 8); nr += __shfl_xor(nr, 8); nm += __shfl_xor(nm, 8);
            if (r == 0) {
                float den = fmaxf(sqrtf(nr * nm), 1e-8f);
                out[(bn * TT + t) * 3 + e] = nu / den;
            }
        }
}

extern "C" void kernel_launch(void* const* d_in, const int* in_sizes, int n_in,
                              void* d_out, int out_size, void* d_ws, size_t ws_size,
                              hipStream_t stream) {
    const float* input       = (const float*)d_in[0];
    const float* h0          = (const float*)d_in[1];
    const float* h1          = (const float*)d_in[2];
    const float* h2          = (const float*)d_in[3];
    const float* memory      = (const float*)d_in[4];
    const float* input_query = (const float*)d_in[5];
    const float* hid_query   = (const float*)d_in[6];
    const float* key_w       = (const float*)d_in[7];
    const float* value_w     = (const float*)d_in[8];
    float* out = (float*)d_out;
    _Float16* ws = (_Float16*)d_ws;   // 65536 bytes used

    hipLaunchKernelGGL(prep_frags, dim3(3), dim3(256), 0, stream,
                       hid_query, key_w, value_w, memory, ws);
    hipLaunchKernelGGL(testam_wave, dim3(16 * 1024 / NWAVES, 3), dim3(128), 0, stream,
                       input, h0, h1, h2, input_query, ws, out);
}

// Round 9
// 206.185 us; speedup vs baseline: 4.0077x; 1.0815x over previous
//
#include <hip/hip_runtime.h>

typedef _Float16 half8 __attribute__((ext_vector_type(8)));
typedef __fp16 fp16x2 __attribute__((ext_vector_type(2)));
typedef float floatx4 __attribute__((ext_vector_type(4)));
typedef unsigned int uint;
typedef uint uint4t __attribute__((ext_vector_type(4)));

namespace {
constexpr int TT = 48, HID = 64, MH = 32, MS = 20;
constexpr int NWAVES = 4;         // waves per block (independent bn, same expert)
// d_ws offsets in half elements (total 32768 halves = 64 KiB)
constexpr int WS_WV   = 0;        // value_w B-frags: [e][kk][nb] * 512
constexpr int WS_MEMA = 6144;     // mem A-frags (rows s, zero s>=20): 1024
constexpr int WS_MEMB = 7168;     // mem B-frags (k=s, col m, zero s>=20): 1024
constexpr int WS_M    = 8192;     // M^T A-frags: [e][hl][tbG][ak] * 512 (hl=1 unused now)
}

static __device__ inline uint pk2(float a, float b) {
    fp16x2 h = __builtin_amdgcn_cvt_pkrtz(a, b);
    return __builtin_bit_cast(uint, h);
}
static __device__ inline half8 mk8(uint a, uint b, uint c, uint d) {
    uint4t u = {a, b, c, d};
    return __builtin_bit_cast(half8, u);
}
static __device__ inline uint pkadd(uint a, uint b) {
    fp16x2 x = __builtin_bit_cast(fp16x2, a);
    fp16x2 y = __builtin_bit_cast(fp16x2, b);
    fp16x2 z = x + y;                      // v_pk_add_f16
    return __builtin_bit_cast(uint, z);
}
// C-layout -> fragment regroup (verified pattern from rounds 6-8):
// combine two 16-row source blocks p0/p1 (each pk-packed [d=0,1]) into one half8.
static __device__ inline half8 regroup2(const uint p0[2], const uint p1[2],
                                        int laneA, bool hiT) {
    uint w[4];
    #pragma unroll
    for (int d = 0; d < 2; ++d) {
        int a0 = __shfl((int)p0[d], laneA);
        int a1 = __shfl((int)p1[d], laneA);
        int b0 = __shfl((int)p0[d], laneA + 16);
        int b1 = __shfl((int)p1[d], laneA + 16);
        w[d]     = hiT ? (uint)a1 : (uint)a0;
        w[2 + d] = hiT ? (uint)b1 : (uint)b0;
    }
    return mk8(w[0], w[1], w[2], w[3]);
}
// third block + zero pad (rows 48..63)
static __device__ inline half8 regroup1pad(const uint p2[2], int laneA, bool hiT) {
    uint w[4];
    #pragma unroll
    for (int d = 0; d < 2; ++d) {
        int a2 = __shfl((int)p2[d], laneA);
        int b2 = __shfl((int)p2[d], laneA + 16);
        w[d]     = hiT ? 0u : (uint)a2;
        w[2 + d] = hiT ? 0u : (uint)b2;
    }
    return mk8(w[0], w[1], w[2], w[3]);
}

// Prep: per-expert M = Wq*Wk^T (fp32) -> M^T A-frags; value_w B-frags; mem frags.
__global__ __launch_bounds__(256)
void prep_frags(const float* __restrict__ hid_query,
                const float* __restrict__ key_w,
                const float* __restrict__ value_w,
                const float* __restrict__ memory,
                _Float16* __restrict__ ws)
{
    const int e = blockIdx.x, tid = threadIdx.x;
    __shared__ float sWq[HID * MH], sWk[HID * MH], sM[HID * HID];
    for (int i = tid; i < HID * MH; i += 256) {
        sWq[i] = hid_query[e * HID * MH + i];
        sWk[i] = key_w[e * HID * MH + i];
    }
    __syncthreads();
    for (int i = tid; i < HID * HID; i += 256) {
        int a = i >> 6, b = i & 63;
        float acc = 0.f;
        #pragma unroll
        for (int m = 0; m < MH; ++m) acc = fmaf(sWq[a * MH + m], sWk[b * MH + m], acc);
        sM[i] = acc;
    }
    __syncthreads();
    // M^T A-frags: lane l elem j of frag [hl][tbG][ak] = M[32ak+8*(l>>4)+j][16tbG+(l&15)]
    for (int i = tid; i < 16 * 512; i += 256) {
        int j = i & 7, lane = (i >> 3) & 63, ak = (i >> 9) & 1, tbG = (i >> 10) & 3, hl = (i >> 12) & 1;
        float v = sM[(32 * ak + 8 * (lane >> 4) + j) * 64 + 16 * tbG + (lane & 15)];
        _Float16 hi = (_Float16)v;
        ws[WS_M + (size_t)((((e * 2 + hl) * 4 + tbG) * 2 + ak) << 9) + (i & 511)] =
            hl ? (_Float16)(v - (float)hi) : hi;
    }
    // value_w B-frags: frag [kk][nb]: W[kk*32+(l>>4)*8+j][nb*16+(l&15)]
    for (int i = tid; i < 2048; i += 256) {
        int j = i & 7, lane = (i >> 3) & 63, nb = (i >> 9) & 1, kk = (i >> 10) & 1;
        int h = kk * 32 + (lane >> 4) * 8 + j;
        int m = nb * 16 + (lane & 15);
        ws[WS_WV + e * 2048 + (i & 2047)] = (_Float16)value_w[((size_t)e * HID + h) * MH + m];
    }
    if (e == 0) {
        for (int i = tid; i < 1024; i += 256) {
            int j = i & 7, lane = (i >> 3) & 63, sb = i >> 9;
            int s = 16 * sb + (lane & 15);
            int m = (lane >> 4) * 8 + j;
            ws[WS_MEMA + i] = (s < MS) ? (_Float16)memory[s * MH + m] : (_Float16)0.f;
        }
        for (int i = tid; i < 1024; i += 256) {
            int j = i & 7, lane = (i >> 3) & 63, nb = i >> 9;
            int s = (lane >> 4) * 8 + j;
            int m = 16 * nb + (lane & 15);
            ws[WS_MEMB + i] = (s < MS) ? (_Float16)memory[s * MH + m] : (_Float16)0.f;
        }
    }
}

// One wave per (bn, expert); 4 independent waves per block. NO LDS, no barriers.
__global__ __launch_bounds__(256, 4)
void testam_wave(const float* __restrict__ input,
                 const float* __restrict__ h0,
                 const float* __restrict__ h1,
                 const float* __restrict__ h2,
                 const float* __restrict__ input_query,
                 const _Float16* __restrict__ ws,
                 float* __restrict__ out)
{
    const int tid  = threadIdx.x;
    const int wid  = tid >> 6;
    const int lane = tid & 63;
    const int r = lane & 15, g = lane >> 4;
    const size_t bn = (size_t)blockIdx.x * NWAVES + wid;
    const int e = blockIdx.y;

    const int laneA = (g & 1) * 32 + r;
    const bool hiT = (g >= 2);

    const float* hp = (e == 0) ? h0 : (e == 1 ? h1 : h2);
    const float* hb = hp + bn * (size_t)(TT * HID);

    // ---- h A-frags, single f16 (RNE casts) ----
    half8 Ah[3][2];
    #pragma unroll
    for (int tb = 0; tb < 3; ++tb)
        #pragma unroll
        for (int kk = 0; kk < 2; ++kk) {
            const float* src = hb + (tb * 16 + r) * HID + kk * 32 + g * 8;
            float4 x0 = *(const float4*)src;
            float4 x1 = *(const float4*)(src + 4);
            half8 hi;
            hi[0] = (_Float16)x0.x; hi[1] = (_Float16)x0.y;
            hi[2] = (_Float16)x0.z; hi[3] = (_Float16)x0.w;
            hi[4] = (_Float16)x1.x; hi[5] = (_Float16)x1.y;
            hi[6] = (_Float16)x1.z; hi[7] = (_Float16)x1.w;
            Ah[tb][kk] = hi;
        }

    // ---- E' via G^T = M^T h^T, all in registers (M single f16) ----
    floatx4 E[3][3];
    #pragma unroll
    for (int tb = 0; tb < 3; ++tb)
        #pragma unroll
        for (int nb = 0; nb < 3; ++nb) E[tb][nb] = (floatx4)0.f;

    #pragma unroll
    for (int kk = 0; kk < 2; ++kk) {
        floatx4 Gacc[2][3];
        #pragma unroll
        for (int t = 0; t < 2; ++t)
            #pragma unroll
            for (int nb = 0; nb < 3; ++nb) Gacc[t][nb] = (floatx4)0.f;
        #pragma unroll
        for (int tbL = 0; tbL < 2; ++tbL) {
            const int tbG = kk * 2 + tbL;
            #pragma unroll
            for (int ak = 0; ak < 2; ++ak) {
                half8 Mhi = *(const half8*)(ws + WS_M + (size_t)((((e * 2 + 0) * 4 + tbG) * 2 + ak) * 64 + lane) * 8);
                #pragma unroll
                for (int nb = 0; nb < 3; ++nb)
                    Gacc[tbL][nb] = __builtin_amdgcn_mfma_f32_16x16x32_f16(Mhi, Ah[nb][ak], Gacc[tbL][nb], 0, 0, 0);
            }
        }
        #pragma unroll
        for (int nb = 0; nb < 3; ++nb) {
            uint p0[2], p1[2];
            #pragma unroll
            for (int d = 0; d < 2; ++d) {
                p0[d] = pk2(Gacc[0][nb][2 * d], Gacc[0][nb][2 * d + 1]);
                p1[d] = pk2(Gacc[1][nb][2 * d], Gacc[1][nb][2 * d + 1]);
            }
            half8 Bh = regroup2(p0, p1, laneA, hiT);
            #pragma unroll
            for (int tb = 0; tb < 3; ++tb)
                E[tb][nb] = __builtin_amdgcn_mfma_f32_16x16x32_f16(Ah[tb][kk], Bh, E[tb][nb], 0, 0, 0);
        }
    }

    // ---- softmax over s per t-col; numerators only ----
    #pragma unroll
    for (int nb = 0; nb < 3; ++nb) {
        float m = E[0][nb][0];
        #pragma unroll
        for (int tb = 0; tb < 3; ++tb)
            #pragma unroll
            for (int rr = 0; rr < 4; ++rr) m = fmaxf(m, E[tb][nb][rr]);
        m = fmaxf(m, __shfl_xor(m, 16));
        m = fmaxf(m, __shfl_xor(m, 32));
        #pragma unroll
        for (int tb = 0; tb < 3; ++tb)
            #pragma unroll
            for (int rr = 0; rr < 4; ++rr) E[tb][nb][rr] = __expf(E[tb][nb][rr] - m);
    }

    // ---- P'^T A-frags (register regroup, zero pad rows 48..63) ----
    half8 PF[3][2];
    #pragma unroll
    for (int tbT = 0; tbT < 3; ++tbT) {
        uint pk[3][2];
        #pragma unroll
        for (int t = 0; t < 3; ++t)
            #pragma unroll
            for (int d = 0; d < 2; ++d)
                pk[t][d] = pk2(E[t][tbT][2 * d], E[t][tbT][2 * d + 1]);
        PF[tbT][0] = regroup2(pk[0], pk[1], laneA, hiT);
        PF[tbT][1] = regroup1pad(pk[2], laneA, hiT);
    }

    // ---- v projection (Ah last use) + register regroup to PV B-frags ----
    half8 vb[2][2];   // [nb][kk]
    {
        half8 WV[2][2];
        #pragma unroll
        for (int kk = 0; kk < 2; ++kk)
            #pragma unroll
            for (int nb = 0; nb < 2; ++nb)
                WV[kk][nb] = *(const half8*)(ws + WS_WV + e * 2048 + (size_t)((kk * 2 + nb) * 64 + lane) * 8);
        floatx4 vacc[3][2];
        #pragma unroll
        for (int tb = 0; tb < 3; ++tb) { vacc[tb][0] = (floatx4)0.f; vacc[tb][1] = (floatx4)0.f; }
        #pragma unroll
        for (int kk = 0; kk < 2; ++kk)
            #pragma unroll
            for (int tb = 0; tb < 3; ++tb)
                #pragma unroll
                for (int nb = 0; nb < 2; ++nb)
                    vacc[tb][nb] = __builtin_amdgcn_mfma_f32_16x16x32_f16(Ah[tb][kk], WV[kk][nb], vacc[tb][nb], 0, 0, 0);
        #pragma unroll
        for (int nb = 0; nb < 2; ++nb) {
            uint pkv[3][2];
            #pragma unroll
            for (int tb = 0; tb < 3; ++tb)
                #pragma unroll
                for (int d = 0; d < 2; ++d)
                    pkv[tb][d] = pk2(vacc[tb][nb][2 * d], vacc[tb][nb][2 * d + 1]);
            vb[nb][0] = regroup2(pkv[0], pkv[1], laneA, hiT);
            vb[nb][1] = regroup1pad(pkv[2], laneA, hiT);
        }
    }

    // ---- att = P'^T @ v ----
    floatx4 att[3][2];
    #pragma unroll
    for (int tb = 0; tb < 3; ++tb) { att[tb][0] = (floatx4)0.f; att[tb][1] = (floatx4)0.f; }
    #pragma unroll
    for (int kk = 0; kk < 2; ++kk)
        #pragma unroll
        for (int tb = 0; tb < 3; ++tb) {
            att[tb][0] = __builtin_amdgcn_mfma_f32_16x16x32_f16(PF[tb][kk], vb[0][kk], att[tb][0], 0, 0, 0);
            att[tb][1] = __builtin_amdgcn_mfma_f32_16x16x32_f16(PF[tb][kk], vb[1][kk], att[tb][1], 0, 0, 0);
        }

    // ---- phase A: memory read-out, all-register ----
    half8 memA0 = *(const half8*)(ws + WS_MEMA + (size_t)lane * 8);
    half8 memA1 = *(const half8*)(ws + WS_MEMA + (size_t)(64 + lane) * 8);
    half8 memB0 = *(const half8*)(ws + WS_MEMB + (size_t)lane * 8);
    half8 memB1 = *(const half8*)(ws + WS_MEMB + (size_t)(64 + lane) * 8);

    float4 iqa = *(const float4*)(input_query + g * 8);
    float4 iqb = *(const float4*)(input_query + g * 8 + 4);
    float4 iqc = *(const float4*)(input_query + 32 + g * 8);
    float4 iqd = *(const float4*)(input_query + 32 + g * 8 + 4);
    float iq0[8] = {iqa.x, iqa.y, iqa.z, iqa.w, iqb.x, iqb.y, iqb.z, iqb.w};
    float iq1[8] = {iqc.x, iqc.y, iqc.z, iqc.w, iqd.x, iqd.y, iqd.z, iqd.w};

    floatx4 Em[2][3];
    #pragma unroll
    for (int tb = 0; tb < 3; ++tb) {
        const float2 in2 = *(const float2*)(input + bn * 96 + (16 * tb + r) * 2);
        half8 qb;
        #pragma unroll
        for (int j = 0; j < 8; ++j)
            qb[j] = (_Float16)(in2.x * iq0[j] + in2.y * iq1[j]);
        Em[0][tb] = __builtin_amdgcn_mfma_f32_16x16x32_f16(memA0, qb, (floatx4)0.f, 0, 0, 0);
        Em[1][tb] = __builtin_amdgcn_mfma_f32_16x16x32_f16(memA1, qb, (floatx4)0.f, 0, 0, 0);
    }
    floatx4 mems[3][2];
    #pragma unroll
    for (int tb = 0; tb < 3; ++tb) {
        float mx = Em[0][tb][0];
        #pragma unroll
        for (int rr = 1; rr < 4; ++rr) mx = fmaxf(mx, Em[0][tb][rr]);
        #pragma unroll
        for (int rr = 0; rr < 4; ++rr) mx = fmaxf(mx, Em[1][tb][rr]);
        mx = fmaxf(mx, __shfl_xor(mx, 16));
        mx = fmaxf(mx, __shfl_xor(mx, 32));
        uint pA0[2], pA1[2];
        #pragma unroll
        for (int d = 0; d < 2; ++d) {
            pA0[d] = pk2(__expf(Em[0][tb][2 * d] - mx), __expf(Em[0][tb][2 * d + 1] - mx));
            pA1[d] = pk2(__expf(Em[1][tb][2 * d] - mx), __expf(Em[1][tb][2 * d + 1] - mx));
        }
        half8 pA = regroup2(pA0, pA1, laneA, hiT);
        mems[tb][0] = __builtin_amdgcn_mfma_f32_16x16x32_f16(pA, memB0, (floatx4)0.f, 0, 0, 0);
        mems[tb][1] = __builtin_amdgcn_mfma_f32_16x16x32_f16(pA, memB1, (floatx4)0.f, 0, 0, 0);
    }

    // ---- cosine(att, memories); nu in f32, (nr,nm) packed f16 (scaled 1/64) ----
    #pragma unroll
    for (int tb = 0; tb < 3; ++tb)
        #pragma unroll
        for (int rr = 0; rr < 4; ++rr) {
            int t = 16 * tb + 4 * g + rr;
            float a0 = att[tb][0][rr], a1 = att[tb][1][rr];
            float m0 = mems[tb][0][rr], m1 = mems[tb][1][rr];
            float nu = a0 * m0 + a1 * m1;
            uint nrm = pk2((a0 * a0 + a1 * a1) * 0.015625f,
                           (m0 * m0 + m1 * m1) * 0.015625f);
            nu += __shfl_xor(nu, 1); nrm = pkadd(nrm, (uint)__shfl_xor((int)nrm, 1));
            nu += __shfl_xor(nu, 2); nrm = pkadd(nrm, (uint)__shfl_xor((int)nrm, 2));
            nu += __shfl_xor(nu, 4); nrm = pkadd(nrm, (uint)__shfl_xor((int)nrm, 4));
            nu += __shfl_xor(nu, 8); nrm = pkadd(nrm, (uint)__shfl_xor((int)nrm, 8));
            if (r == 0) {
                fp16x2 f = __builtin_bit_cast(fp16x2, nrm);
                float den = fmaxf(64.f * sqrtf((float)f[0] * (float)f[1]), 1e-8f);
                out[(bn * TT + t) * 3 + e] = nu / den;
            }
        }
}

extern "C" void kernel_launch(void* const* d_in, const int* in_sizes, int n_in,
                              void* d_out, int out_size, void* d_ws, size_t ws_size,
                              hipStream_t stream) {
    const float* input       = (const float*)d_in[0];
    const float* h0          = (const float*)d_in[1];
    const float* h1          = (const float*)d_in[2];
    const float* h2          = (const float*)d_in[3];
    const float* memory      = (const float*)d_in[4];
    const float* input_query = (const float*)d_in[5];
    const float* hid_query   = (const float*)d_in[6];
    const float* key_w       = (const float*)d_in[7];
    const float* value_w     = (const float*)d_in[8];
    float* out = (float*)d_out;
    _Float16* ws = (_Float16*)d_ws;   // 65536 bytes used

    hipLaunchKernelGGL(prep_frags, dim3(3), dim3(256), 0, stream,
                       hid_query, key_w, value_w, memory, ws);
    hipLaunchKernelGGL(testam_wave, dim3(16 * 1024 / NWAVES, 3), dim3(256), 0, stream,
                       input, h0, h1, h2, input_query, ws, out);
}